// Round 1
// baseline (12316.420 us; speedup 1.0000x reference)
//
#include <hip/hip_runtime.h>
#include <cstdint>
#include <cstddef>
#include <math.h>

// ---------------------------------------------------------------------------
// RTRBM forward with CD-2 Gibbs sampling, bit-exact JAX threefry reproduction.
// Strategy: fp64 logits (true-value arithmetic), round p to f32, exact
// threefry2x32-20 uniforms. PARTITIONABLE=1 matches jax>=0.5 default
// (jax_threefry_partitionable=True). If validation fails at absmax 1.0,
// flip to 0 (legacy counter-pair mode).
// ---------------------------------------------------------------------------
#define PARTITIONABLE 1

#define NVV 4096
#define NHH 1024
#define TT  64
#define BB  32
// element strides
#define TB  (TT * BB)   // 2048

__host__ __device__ __forceinline__ void tf2x32(uint32_t k0, uint32_t k1,
                                                uint32_t x0, uint32_t x1,
                                                uint32_t& o0, uint32_t& o1) {
  uint32_t ks2 = k0 ^ k1 ^ 0x1BD11BDAu;
#define TF_RND(r) { x0 += x1; x1 = (x1 << (r)) | (x1 >> (32 - (r))); x1 ^= x0; }
  x0 += k0; x1 += k1;
  TF_RND(13) TF_RND(15) TF_RND(26) TF_RND(6)
  x0 += k1;  x1 += ks2 + 1u;
  TF_RND(17) TF_RND(29) TF_RND(16) TF_RND(24)
  x0 += ks2; x1 += k0 + 2u;
  TF_RND(13) TF_RND(15) TF_RND(26) TF_RND(6)
  x0 += k0;  x1 += k1 + 3u;
  TF_RND(17) TF_RND(29) TF_RND(16) TF_RND(24)
  x0 += k1;  x1 += ks2 + 4u;
  TF_RND(13) TF_RND(15) TF_RND(26) TF_RND(6)
  x0 += ks2; x1 += k0 + 5u;
#undef TF_RND
  o0 = x0; o1 = x1;
}

// jax.random.uniform(key, shape, f32) element j (row-major flat index).
__device__ __forceinline__ float tf_uniform(uint32_t k0, uint32_t k1,
                                            uint32_t j, uint32_t half) {
  uint32_t o0, o1, bits;
#if PARTITIONABLE
  (void)half;
  tf2x32(k0, k1, 0u, j, o0, o1);
  bits = o0 ^ o1;                      // 32-bit path: xor of halves
#else
  uint32_t c0 = (j < half) ? j : (j - half);
  tf2x32(k0, k1, c0, c0 + half, o0, o1);
  bits = (j < half) ? o0 : o1;
#endif
  uint32_t fb = (bits >> 9) | 0x3f800000u;
  return __uint_as_float(fb) - 1.0f;
}

__device__ __forceinline__ void sigmoid_sample(double logit, uint32_t k0, uint32_t k1,
                                               uint32_t j, uint32_t half,
                                               float& p32, float& bit) {
  double pd = 1.0 / (1.0 + exp(-logit));
  p32 = (float)pd;                      // reference keeps p in f32
  float u = tf_uniform(k0, k1, j, half);
  bit = (u < p32) ? 1.0f : 0.0f;
}

// ---------------------------------------------------------------------------
// hb = b_init broadcast (t == 0)
__global__ void hb_init_k(const float* __restrict__ b_init, double* __restrict__ hb) {
  int j = blockIdx.x * 256 + threadIdx.x;          // 32768
  hb[j] = (double)b_init[j >> 5];
}

// hb[n,b] = sum_k U[n,k] * r[k*xs + b] + b_h[n]   (M=1024, K=1024)
// block: 1024 thr = 32 b x 4 n x 8 ksplit (chunk 128); grid 256.
__global__ __launch_bounds__(1024)
void hb_gemm_k(const float* __restrict__ U, const float* __restrict__ r, long xs,
               const float* __restrict__ b_h, double* __restrict__ hb) {
  int tid = threadIdx.x;
  int b   = tid & 31;
  int n_l = (tid >> 5) & 3;
  int ks  = tid >> 7;                               // 0..7
  int n   = blockIdx.x * 4 + n_l;
  const float* urow = U + (size_t)n * NHH;
  const float* xp   = r + (long)(ks * 128) * xs + b;
  double a0 = 0, a1 = 0, a2 = 0, a3 = 0;
  int kbeg = ks * 128;
  for (int k = kbeg; k < kbeg + 128; k += 4) {
    float4 uv = *(const float4*)(urow + k);
    float x0 = xp[0], x1 = xp[xs], x2 = xp[2 * xs], x3 = xp[3 * xs];
    xp += 4 * xs;
    a0 += (double)uv.x * (double)x0;
    a1 += (double)uv.y * (double)x1;
    a2 += (double)uv.z * (double)x2;
    a3 += (double)uv.w * (double)x3;
  }
  __shared__ double red[4][32][8];
  red[n_l][b][ks] = (a0 + a1) + (a2 + a3);
  __syncthreads();
  if (tid < 128) {
    int nl2 = tid >> 5, b2 = tid & 31;
    int n2  = blockIdx.x * 4 + nl2;
    double s = 0;
#pragma unroll
    for (int q = 0; q < 8; q++) s += red[nl2][b2][q];
    hb[n2 * 32 + b2] = s + (double)b_h[n2];
  }
}

// Type A: logit[n,b] = sum_k W[n,k] * x[k*xs + b] + hb[n,b]; sigmoid; sample.
// M=1024, K=4096. block: 1024 thr = 32 b x 4 n x 8 ksplit (chunk 512); grid 256.
__global__ __launch_bounds__(1024)
void gemmA_sample_k(const float* __restrict__ W, const float* __restrict__ x, long xs,
                    const double* __restrict__ hb,
                    float* __restrict__ bit_ws,          // [NHH*32], always written
                    float* __restrict__ p_out,           // optional, idx n*TB + b
                    float* __restrict__ bit_out,         // optional, idx n*TB + b
                    uint32_t key0, uint32_t key1) {
  int tid = threadIdx.x;
  int b   = tid & 31;
  int n_l = (tid >> 5) & 3;
  int ks  = tid >> 7;                               // 0..7
  int n   = blockIdx.x * 4 + n_l;
  const float* wrow = W + (size_t)n * NVV;
  const float* xp   = x + (long)(ks * 512) * xs + b;
  double a0 = 0, a1 = 0, a2 = 0, a3 = 0;
  int kbeg = ks * 512;
  for (int k = kbeg; k < kbeg + 512; k += 4) {
    float4 wv = *(const float4*)(wrow + k);
    float x0 = xp[0], x1 = xp[xs], x2 = xp[2 * xs], x3 = xp[3 * xs];
    xp += 4 * xs;
    a0 += (double)wv.x * (double)x0;
    a1 += (double)wv.y * (double)x1;
    a2 += (double)wv.z * (double)x2;
    a3 += (double)wv.w * (double)x3;
  }
  __shared__ double red[4][32][8];
  red[n_l][b][ks] = (a0 + a1) + (a2 + a3);
  __syncthreads();
  if (tid < 128) {
    int nl2 = tid >> 5, b2 = tid & 31;
    int n2  = blockIdx.x * 4 + nl2;
    double s = 0;
#pragma unroll
    for (int q = 0; q < 8; q++) s += red[nl2][b2][q];
    double logit = s + hb[n2 * 32 + b2];
    uint32_t j = (uint32_t)(n2 * 32 + b2);
    float p32, bit;
    sigmoid_sample(logit, key0, key1, j, (uint32_t)(NHH * BB / 2), p32, bit);
    bit_ws[j] = bit;
    if (p_out)   p_out[(size_t)n2 * TB + b2]   = p32;
    if (bit_out) bit_out[(size_t)n2 * TB + b2] = bit;
  }
}

// Type B: logit[i,b] = sum_n W[n,i] * x[n*32 + b] + b_v[i]; sigmoid; sample.
// M=4096, K=1024. block: 1024 thr = 16 i x 32 b x 2 ksplit (chunk 512); grid 256.
__global__ __launch_bounds__(1024)
void gemmB_sample_k(const float* __restrict__ W, const float* __restrict__ x,
                    const float* __restrict__ b_v,
                    float* __restrict__ bit_ws,          // optional [NVV*32]
                    float* __restrict__ bit_out,         // optional, idx i*TB + b
                    uint32_t key0, uint32_t key1) {
  int tid = threadIdx.x;
  int i_l = tid & 15;
  int b   = (tid >> 4) & 31;
  int ks  = tid >> 9;                               // 0..1
  int i   = blockIdx.x * 16 + i_l;
  const float* wp = W + (size_t)(ks * 512) * NVV + i;
  const float* xp = x + (size_t)(ks * 512) * 32 + b;
  double a0 = 0, a1 = 0, a2 = 0, a3 = 0;
  for (int k = 0; k < 512; k += 4) {
    float w0 = wp[0], w1 = wp[NVV], w2 = wp[2 * NVV], w3 = wp[3 * NVV];
    float x0 = xp[0], x1 = xp[32], x2 = xp[64], x3 = xp[96];
    wp += 4 * NVV; xp += 128;
    a0 += (double)w0 * (double)x0;
    a1 += (double)w1 * (double)x1;
    a2 += (double)w2 * (double)x2;
    a3 += (double)w3 * (double)x3;
  }
  __shared__ double red[16][32][2];
  red[i_l][b][ks] = (a0 + a1) + (a2 + a3);
  __syncthreads();
  if (tid < 512) {
    int il2 = tid & 15, b2 = tid >> 4;
    int i2  = blockIdx.x * 16 + il2;
    double s = red[il2][b2][0] + red[il2][b2][1];
    double logit = s + (double)b_v[i2];
    uint32_t j = (uint32_t)(i2 * 32 + b2);
    float p32, bit;
    sigmoid_sample(logit, key0, key1, j, (uint32_t)(NVV * BB / 2), p32, bit);
    (void)p32;
    if (bit_ws)  bit_ws[j] = bit;
    if (bit_out) bit_out[(size_t)i2 * TB + b2] = bit;
  }
}

// ---------------------------------------------------------------------------
// Host-side key tree (pure CPU, graph-capture safe: keys become kernel args).
static void tf_split(const uint32_t key[2], int n, uint32_t out[][2]) {
#if PARTITIONABLE
  for (int i = 0; i < n; i++)
    tf2x32(key[0], key[1], 0u, (uint32_t)i, out[i][0], out[i][1]);
#else
  uint32_t flat[256];  // n <= 63 here
  for (int i = 0; i < n; i++)
    tf2x32(key[0], key[1], (uint32_t)i, (uint32_t)(n + i), flat[i], flat[n + i]);
  for (int i = 0; i < n; i++) { out[i][0] = flat[2 * i]; out[i][1] = flat[2 * i + 1]; }
#endif
}

extern "C" void kernel_launch(void* const* d_in, const int* in_sizes, int n_in,
                              void* d_out, int out_size, void* d_ws, size_t ws_size,
                              hipStream_t stream) {
  const float* v      = (const float*)d_in[0];   // [NVV, TT, BB]
  const float* W      = (const float*)d_in[1];   // [NHH, NVV]
  const float* U      = (const float*)d_in[2];   // [NHH, NHH]
  const float* b_v    = (const float*)d_in[3];   // [NVV]
  const float* b_h    = (const float*)d_in[4];   // [NHH]
  const float* b_init = (const float*)d_in[5];   // [NHH]

  float* out    = (float*)d_out;
  float* vmodel = out;                                   // NVV*TT*BB = 8388608
  float* rmodel = out + (size_t)NVV * TB;                // NHH*TT*BB = 2097152
  float* rt     = rmodel + (size_t)NHH * TB;

  char* wsb = (char*)d_ws;
  double* hb   = (double*)wsb;                           // 32768 * 8  = 256 KiB
  float* h_ws  = (float*)(wsb + 262144);                 // 32768 * 4
  float* h2_ws = (float*)(wsb + 262144 + 131072);        // 32768 * 4
  float* vm_ws = (float*)(wsb + 262144 + 262144);        // 131072 * 4 = 512 KiB

  // ---- key tree: key(42) -> (k0, ks); t=0 uses split(k0,4); scan t uses
  // split(split(ks,63)[t-1], 4).
  uint32_t root[2] = {0u, 42u};
  uint32_t rk[2][2];  tf_split(root, 2, rk);             // rk[0]=k0, rk[1]=ks
  uint32_t tk[63][2]; tf_split(rk[1], 63, tk);
  uint32_t ck[TT][4][2];
  tf_split(rk[0], 4, ck[0]);
  for (int t = 1; t < TT; t++) tf_split(tk[t - 1], 4, ck[t]);

  for (int t = 0; t < TT; t++) {
    // phase 0: hid_bias (fp64)
    if (t == 0) {
      hipLaunchKernelGGL(hb_init_k, dim3(128), dim3(256), 0, stream, b_init, hb);
    } else {
      // r_lag read back from rt output written at step t-1
      hipLaunchKernelGGL(hb_gemm_k, dim3(256), dim3(1024), 0, stream,
                         U, rt + (size_t)(t - 1) * BB, (long)TB, b_h, hb);
    }
    // phase 1: r_data = sigmoid(W @ v_t + hb); h = bern(keys[0], r)
    hipLaunchKernelGGL(gemmA_sample_k, dim3(256), dim3(1024), 0, stream,
                       W, v + (size_t)t * BB, (long)TB, hb,
                       h_ws, rt + (size_t)t * BB, (float*)nullptr,
                       ck[t][0][0], ck[t][0][1]);
    // phase 2: vm = bern(keys[1], sigmoid(W^T @ h + b_v))
    hipLaunchKernelGGL(gemmB_sample_k, dim3(256), dim3(1024), 0, stream,
                       W, h_ws, b_v, vm_ws, (float*)nullptr,
                       ck[t][1][0], ck[t][1][1]);
    // phase 3: h2 = bern(keys[2], sigmoid(W @ vm + hb)) -> r_model
    hipLaunchKernelGGL(gemmA_sample_k, dim3(256), dim3(1024), 0, stream,
                       W, vm_ws, (long)32, hb,
                       h2_ws, (float*)nullptr, rmodel + (size_t)t * BB,
                       ck[t][2][0], ck[t][2][1]);
    // phase 4: v_model = bern(keys[3], sigmoid(W^T @ h2 + b_v))
    hipLaunchKernelGGL(gemmB_sample_k, dim3(256), dim3(1024), 0, stream,
                       W, h2_ws, b_v, (float*)nullptr, vmodel + (size_t)t * BB,
                       ck[t][3][0], ck[t][3][1]);
  }

  (void)in_sizes; (void)n_in; (void)out_size; (void)ws_size;
}

// Round 2
// 6350.764 us; speedup vs baseline: 1.9394x; 1.9394x over previous
//
#include <hip/hip_runtime.h>
#include <cstdint>
#include <cstddef>
#include <math.h>

// ---------------------------------------------------------------------------
// RTRBM forward, CD-2 Gibbs, bit-exact JAX threefry (partitionable mode —
// validated round 1). fp64 logits (true-value arithmetic; reassociation-safe),
// p rounded to f32 before the Bernoulli compare.
// Round 2: 4-row register tiles (amortize cvt), float4 column loads in the
// W^T phases, hb GEMM fused into phase 1. 256 dispatches (was 321).
// ---------------------------------------------------------------------------

#define NVV 4096
#define NHH 1024
#define TT  64
#define BB  32
#define TB  2048   // TT*BB

__host__ __device__ __forceinline__ void tf2x32(uint32_t k0, uint32_t k1,
                                                uint32_t x0, uint32_t x1,
                                                uint32_t& o0, uint32_t& o1) {
  uint32_t ks2 = k0 ^ k1 ^ 0x1BD11BDAu;
#define TF_RND(r) { x0 += x1; x1 = (x1 << (r)) | (x1 >> (32 - (r))); x1 ^= x0; }
  x0 += k0; x1 += k1;
  TF_RND(13) TF_RND(15) TF_RND(26) TF_RND(6)
  x0 += k1;  x1 += ks2 + 1u;
  TF_RND(17) TF_RND(29) TF_RND(16) TF_RND(24)
  x0 += ks2; x1 += k0 + 2u;
  TF_RND(13) TF_RND(15) TF_RND(26) TF_RND(6)
  x0 += k0;  x1 += k1 + 3u;
  TF_RND(17) TF_RND(29) TF_RND(16) TF_RND(24)
  x0 += k1;  x1 += ks2 + 4u;
  TF_RND(13) TF_RND(15) TF_RND(26) TF_RND(6)
  x0 += ks2; x1 += k0 + 5u;
#undef TF_RND
  o0 = x0; o1 = x1;
}

__device__ __forceinline__ float tf_uniform(uint32_t k0, uint32_t k1, uint32_t j) {
  uint32_t o0, o1;
  tf2x32(k0, k1, 0u, j, o0, o1);
  uint32_t bits = o0 ^ o1;                    // partitionable 32-bit path
  return __uint_as_float((bits >> 9) | 0x3f800000u) - 1.0f;
}

__device__ __forceinline__ void bern_sample(double logit, uint32_t k0, uint32_t k1,
                                            uint32_t j, float& p32, float& bit) {
  double pd = 1.0 / (1.0 + exp(-logit));
  p32 = (float)pd;
  float u = tf_uniform(k0, k1, j);
  bit = (u < p32) ? 1.0f : 0.0f;
}

// ---------------------------------------------------------------------------
// dotA: 4 consecutive output rows, row-major weights (row stride RS), CH k's.
// wb -> weights + n0*RS + kbeg ; xp0 -> x + kbeg*xs + b
template<int RS, int CH>
__device__ __forceinline__ void dotA(const float* __restrict__ wb,
                                     const float* __restrict__ xp0,
                                     long xs, double acc[4]) {
  const float* xp = xp0;
#pragma unroll 2
  for (int k = 0; k < CH; k += 4) {
    float4 a0 = *(const float4*)(wb + k);
    float4 a1 = *(const float4*)(wb + RS + k);
    float4 a2 = *(const float4*)(wb + 2 * RS + k);
    float4 a3 = *(const float4*)(wb + 3 * RS + k);
    float f0 = xp[0], f1 = xp[xs], f2 = xp[2 * xs], f3 = xp[3 * xs];
    xp += 4 * xs;
    double d0 = f0, d1 = f1, d2 = f2, d3 = f3;
    acc[0] += a0.x * d0; acc[0] += a0.y * d1; acc[0] += a0.z * d2; acc[0] += a0.w * d3;
    acc[1] += a1.x * d0; acc[1] += a1.y * d1; acc[1] += a1.z * d2; acc[1] += a1.w * d3;
    acc[2] += a2.x * d0; acc[2] += a2.y * d1; acc[2] += a2.z * d2; acc[2] += a2.w * d3;
    acc[3] += a3.x * d0; acc[3] += a3.y * d1; acc[3] += a3.z * d2; acc[3] += a3.w * d3;
  }
}

// dotB: 4 consecutive output rows i0..i0+3 of W^T — read as float4 from
// W[k][i0..i0+3], k stride NVV. x layout [K][32].
template<int CH>
__device__ __forceinline__ void dotB(const float* __restrict__ wp0,
                                     const float* __restrict__ xp0,
                                     double acc[4]) {
  const float* wp = wp0;
  const float* xp = xp0;
#pragma unroll 2
  for (int k = 0; k < CH; k += 4) {
    float4 c0 = *(const float4*)(wp);
    float4 c1 = *(const float4*)(wp + NVV);
    float4 c2 = *(const float4*)(wp + 2 * NVV);
    float4 c3 = *(const float4*)(wp + 3 * NVV);
    wp += 4 * NVV;
    float f0 = xp[0], f1 = xp[BB], f2 = xp[2 * BB], f3 = xp[3 * BB];
    xp += 4 * BB;
    double d0 = f0, d1 = f1, d2 = f2, d3 = f3;
    acc[0] += c0.x * d0; acc[0] += c1.x * d1; acc[0] += c2.x * d2; acc[0] += c3.x * d3;
    acc[1] += c0.y * d0; acc[1] += c1.y * d1; acc[1] += c2.y * d2; acc[1] += c3.y * d3;
    acc[2] += c0.z * d0; acc[2] += c1.z * d1; acc[2] += c2.z * d2; acc[2] += c3.z * d3;
    acc[3] += c0.w * d0; acc[3] += c1.w * d1; acc[3] += c2.w * d2; acc[3] += c3.w * d3;
  }
}

// ---------------------------------------------------------------------------
// Phase 1: logit = W@v_t + (U@r_lag + b_h | b_init); store hb64; sample h;
// write p to rt. Block: 4 rows x 32 b; 1024 thr = b(32) x ks(32), chunk 128.
__global__ __launch_bounds__(1024)
void kA1(const float* __restrict__ W, const float* __restrict__ v_t,
         const float* __restrict__ U, const float* __restrict__ r_lag,
         const float* __restrict__ b_h, const float* __restrict__ b_init,
         double* __restrict__ hb64, float* __restrict__ h_ws,
         float* __restrict__ rtp, uint32_t key0, uint32_t key1) {
  __shared__ double red[128][32];
  int tid = threadIdx.x;
  int b = tid & 31, ks = tid >> 5;           // ks 0..31
  int n0 = blockIdx.x * 4;

  double acc[4] = {0, 0, 0, 0};
  {
    int kbeg = ks * 128;
    dotA<NVV, 128>(W + (size_t)n0 * NVV + kbeg, v_t + (long)kbeg * TB + b, (long)TB, acc);
  }
#pragma unroll
  for (int r = 0; r < 4; r++) red[ks * 4 + r][b] = acc[r];
  __syncthreads();

  double wsum = 0;
  if (tid < 128) {
    int rl = tid >> 5, b2 = tid & 31;
#pragma unroll
    for (int q = 0; q < 32; q++) wsum += red[q * 4 + rl][b2];
  }
  __syncthreads();

  double ua[4] = {0, 0, 0, 0};
  if (r_lag) {
    int kbeg = ks * 32;
    dotA<NHH, 32>(U + (size_t)n0 * NHH + kbeg, r_lag + (long)kbeg * TB + b, (long)TB, ua);
  }
#pragma unroll
  for (int r = 0; r < 4; r++) red[ks * 4 + r][b] = ua[r];
  __syncthreads();

  if (tid < 128) {
    int rl = tid >> 5, b2 = tid & 31;
    int n = n0 + rl;
    double us = 0;
#pragma unroll
    for (int q = 0; q < 32; q++) us += red[q * 4 + rl][b2];
    double hbv = r_lag ? (us + (double)b_h[n]) : (double)b_init[n];
    hb64[n * 32 + b2] = hbv;
    double logit = wsum + hbv;
    float p32, bit;
    bern_sample(logit, key0, key1, (uint32_t)(n * 32 + b2), p32, bit);
    h_ws[n * 32 + b2] = bit;
    rtp[(size_t)n * TB + b2] = p32;
  }
}

// Phase 3: logit = W@vm + hb64; sample h2 -> h2_ws and rmodel.
__global__ __launch_bounds__(1024)
void kA2(const float* __restrict__ W, const float* __restrict__ vm,
         const double* __restrict__ hb64,
         float* __restrict__ h2_ws, float* __restrict__ rmp,
         uint32_t key0, uint32_t key1) {
  __shared__ double red[128][32];
  int tid = threadIdx.x;
  int b = tid & 31, ks = tid >> 5;
  int n0 = blockIdx.x * 4;

  double acc[4] = {0, 0, 0, 0};
  {
    int kbeg = ks * 128;
    dotA<NVV, 128>(W + (size_t)n0 * NVV + kbeg, vm + (long)kbeg * 32 + b, (long)32, acc);
  }
#pragma unroll
  for (int r = 0; r < 4; r++) red[ks * 4 + r][b] = acc[r];
  __syncthreads();

  if (tid < 128) {
    int rl = tid >> 5, b2 = tid & 31;
    int n = n0 + rl;
    double s = 0;
#pragma unroll
    for (int q = 0; q < 32; q++) s += red[q * 4 + rl][b2];
    double logit = s + hb64[n * 32 + b2];
    float p32, bit;
    bern_sample(logit, key0, key1, (uint32_t)(n * 32 + b2), p32, bit);
    h2_ws[n * 32 + b2] = bit;
    rmp[(size_t)n * TB + b2] = bit;
  }
}

// Phases 2/4: logit = W^T@h + b_v; sample v-side bits.
// Block: 16 rows x 32 b; 1024 thr = b(32) x nl(4) x ks(8), chunk 128.
__global__ __launch_bounds__(1024)
void kB(const float* __restrict__ W, const float* __restrict__ h,
        const float* __restrict__ b_v,
        float* __restrict__ bit32,      // nullable, [NVV][32]
        float* __restrict__ bitT,       // nullable, stride TB (pre-offset t*32)
        uint32_t key0, uint32_t key1) {
  __shared__ double red[128][32];
  int tid = threadIdx.x;
  int b = tid & 31;
  int nl = (tid >> 5) & 3;
  int ks = tid >> 7;                     // 0..7
  int i0 = blockIdx.x * 16 + nl * 4;

  double acc[4] = {0, 0, 0, 0};
  {
    int kbeg = ks * 128;
    dotB<128>(W + (size_t)kbeg * NVV + i0, h + (long)kbeg * 32 + b, acc);
  }
#pragma unroll
  for (int r = 0; r < 4; r++) red[ks * 16 + nl * 4 + r][b] = acc[r];
  __syncthreads();

  if (tid < 512) {
    int rl = tid >> 5, b2 = tid & 31;    // rl 0..15
    int i = blockIdx.x * 16 + rl;
    double s = 0;
#pragma unroll
    for (int q = 0; q < 8; q++) s += red[q * 16 + rl][b2];
    double logit = s + (double)b_v[i];
    float p32, bit;
    bern_sample(logit, key0, key1, (uint32_t)(i * 32 + b2), p32, bit);
    (void)p32;
    if (bit32) bit32[i * 32 + b2] = bit;
    if (bitT)  bitT[(size_t)i * TB + b2] = bit;
  }
}

// ---------------------------------------------------------------------------
static void tf_split(const uint32_t key[2], int n, uint32_t out[][2]) {
  for (int i = 0; i < n; i++)
    tf2x32(key[0], key[1], 0u, (uint32_t)i, out[i][0], out[i][1]);
}

extern "C" void kernel_launch(void* const* d_in, const int* in_sizes, int n_in,
                              void* d_out, int out_size, void* d_ws, size_t ws_size,
                              hipStream_t stream) {
  const float* v      = (const float*)d_in[0];   // [NVV, TT, BB]
  const float* W      = (const float*)d_in[1];   // [NHH, NVV]
  const float* U      = (const float*)d_in[2];   // [NHH, NHH]
  const float* b_v    = (const float*)d_in[3];
  const float* b_h    = (const float*)d_in[4];
  const float* b_init = (const float*)d_in[5];

  float* out    = (float*)d_out;
  float* vmodel = out;                                   // [NVV][TT][BB]
  float* rmodel = out + (size_t)NVV * TB;                // [NHH][TT][BB]
  float* rt     = rmodel + (size_t)NHH * TB;             // [NHH][TT][BB]

  char* wsb = (char*)d_ws;
  double* hb64 = (double*)wsb;                           // 32768 * 8  = 256 KiB
  float* h_ws  = (float*)(wsb + 262144);                 // 32768 * 4
  float* h2_ws = (float*)(wsb + 262144 + 131072);        // 32768 * 4
  float* vm_ws = (float*)(wsb + 262144 + 262144);        // 131072 * 4

  // key tree: key(42) -> (k0, ks); t=0: split(k0,4); t>0: split(split(ks,63)[t-1],4)
  uint32_t root[2] = {0u, 42u};
  uint32_t rk[2][2];  tf_split(root, 2, rk);
  uint32_t tk[63][2]; tf_split(rk[1], 63, tk);
  uint32_t ck[TT][4][2];
  tf_split(rk[0], 4, ck[0]);
  for (int t = 1; t < TT; t++) tf_split(tk[t - 1], 4, ck[t]);

  for (int t = 0; t < TT; t++) {
    hipLaunchKernelGGL(kA1, dim3(256), dim3(1024), 0, stream,
                       W, v + (size_t)t * BB, U,
                       (t ? rt + (size_t)(t - 1) * BB : (const float*)nullptr),
                       b_h, b_init, hb64, h_ws, rt + (size_t)t * BB,
                       ck[t][0][0], ck[t][0][1]);
    hipLaunchKernelGGL(kB, dim3(256), dim3(1024), 0, stream,
                       W, h_ws, b_v, vm_ws, (float*)nullptr,
                       ck[t][1][0], ck[t][1][1]);
    hipLaunchKernelGGL(kA2, dim3(256), dim3(1024), 0, stream,
                       W, vm_ws, hb64, h2_ws, rmodel + (size_t)t * BB,
                       ck[t][2][0], ck[t][2][1]);
    hipLaunchKernelGGL(kB, dim3(256), dim3(1024), 0, stream,
                       W, h2_ws, b_v, (float*)nullptr, vmodel + (size_t)t * BB,
                       ck[t][3][0], ck[t][3][1]);
  }

  (void)in_sizes; (void)n_in; (void)out_size; (void)ws_size;
}

// Round 3
// 4654.168 us; speedup vs baseline: 2.6463x; 1.3645x over previous
//
#include <hip/hip_runtime.h>
#include <cstdint>
#include <cstddef>
#include <math.h>

// ---------------------------------------------------------------------------
// RTRBM forward, CD-2 Gibbs, bit-exact JAX threefry (partitionable mode).
// fp64 logits (true-value arithmetic), p rounded to f32 before compare.
// Round 3: critical-path restructuring. Only the phase-1 recurrence is
// sequential (64 tiny launches); W@v is hoisted upfront and phases 2/3/4 are
// batched over all 64 timesteps into three wide parallel GEMMs with fused
// sample epilogues. 72 dispatches (was 256). fp64 k-split via native f64
// atomics (order-independent at ~1e-16 — far below any Bernoulli margin).
// ---------------------------------------------------------------------------

#define NVV 4096
#define NHH 1024
#define TT  64
#define BB  32
#define CC  2048   // TT*BB columns of the batched GEMMs

__host__ __device__ __forceinline__ void tf2x32(uint32_t k0, uint32_t k1,
                                                uint32_t x0, uint32_t x1,
                                                uint32_t& o0, uint32_t& o1) {
  uint32_t ks2 = k0 ^ k1 ^ 0x1BD11BDAu;
#define TF_RND(r) { x0 += x1; x1 = (x1 << (r)) | (x1 >> (32 - (r))); x1 ^= x0; }
  x0 += k0; x1 += k1;
  TF_RND(13) TF_RND(15) TF_RND(26) TF_RND(6)
  x0 += k1;  x1 += ks2 + 1u;
  TF_RND(17) TF_RND(29) TF_RND(16) TF_RND(24)
  x0 += ks2; x1 += k0 + 2u;
  TF_RND(13) TF_RND(15) TF_RND(26) TF_RND(6)
  x0 += k0;  x1 += k1 + 3u;
  TF_RND(17) TF_RND(29) TF_RND(16) TF_RND(24)
  x0 += k1;  x1 += ks2 + 4u;
  TF_RND(13) TF_RND(15) TF_RND(26) TF_RND(6)
  x0 += ks2; x1 += k0 + 5u;
#undef TF_RND
  o0 = x0; o1 = x1;
}

__device__ __forceinline__ float tf_uniform(uint32_t k0, uint32_t k1, uint32_t j) {
  uint32_t o0, o1;
  tf2x32(k0, k1, 0u, j, o0, o1);
  uint32_t bits = o0 ^ o1;
  return __uint_as_float((bits >> 9) | 0x3f800000u) - 1.0f;
}

__device__ __forceinline__ void bern_sample(double logit, uint32_t k0, uint32_t k1,
                                            uint32_t j, float& p32, float& bit) {
  double pd = 1.0 / (1.0 + exp(-logit));
  p32 = (float)pd;
  float u = tf_uniform(k0, k1, j);
  bit = (u < p32) ? 1.0f : 0.0f;
}

// per-thread step-key: ck = split(key_t, 4)[phase], key_t = t? split(ks,63)[t-1] : k0
__device__ __forceinline__ void step_key(int t, int phase,
                                         uint32_t rk00, uint32_t rk01,
                                         uint32_t rk10, uint32_t rk11,
                                         uint32_t& c0, uint32_t& c1) {
  uint32_t kt0, kt1;
  tf2x32(rk10, rk11, 0u, (uint32_t)(t > 0 ? t - 1 : 0), kt0, kt1);
  if (t == 0) { kt0 = rk00; kt1 = rk01; }
  tf2x32(kt0, kt1, 0u, (uint32_t)phase, c0, c1);
}

// ---------------------------------------------------------------------------
__global__ void zfill(double* __restrict__ p, int n) {
  int i = blockIdx.x * 256 + threadIdx.x;
  if (i < n) p[i] = 0.0;
}

// C[M][CC] += A[M rows, lda stride] @ x[K][CC]   (f64 accumulate, ksplit 4)
// block 256 = cthr(32) x rg(2) x ks(4); 8 rows x 256 cols per block.
// grid = (M/8) * 8 c-blocks. skip_t0: suppress stores for columns with t==0.
__global__ __launch_bounds__(256, 3)
void gemm_acc(const float* __restrict__ A, int lda, const float* __restrict__ x,
              double* __restrict__ C, int Ktot, int skip_t0) {
  int tid  = threadIdx.x;
  int cthr = tid & 31;
  int rg   = (tid >> 5) & 1;
  int ks   = tid >> 6;
  int nb = blockIdx.x >> 3, cb = blockIdx.x & 7;
  int n0 = nb * 8 + rg * 4;
  int c0 = cb * 256 + cthr * 8;
  int kchunk = Ktot >> 2;
  int kbeg = ks * kchunk;

  double acc[32];
#pragma unroll
  for (int q = 0; q < 32; q++) acc[q] = 0.0;

  for (int k = kbeg; k < kbeg + kchunk; k += 4) {
    float ar[4][4];
#pragma unroll
    for (int r = 0; r < 4; r++) {
      float4 q = *(const float4*)(A + (size_t)(n0 + r) * lda + k);
      ar[r][0] = q.x; ar[r][1] = q.y; ar[r][2] = q.z; ar[r][3] = q.w;
    }
#pragma unroll
    for (int kk = 0; kk < 4; kk++) {
      const float* xp = x + (size_t)(k + kk) * CC + c0;
      float4 xlo = *(const float4*)(xp);
      float4 xhi = *(const float4*)(xp + 4);
      double xd[8] = {xlo.x, xlo.y, xlo.z, xlo.w, xhi.x, xhi.y, xhi.z, xhi.w};
#pragma unroll
      for (int r = 0; r < 4; r++) {
        double ad = (double)ar[r][kk];
#pragma unroll
        for (int j = 0; j < 8; j++) acc[r * 8 + j] += ad * xd[j];
      }
    }
  }

  int t = c0 >> 5;                    // uniform per thread (8 cols in one t)
  if (!(skip_t0 && t == 0)) {
    double* Cp = C + (size_t)n0 * CC + c0;
#pragma unroll
    for (int r = 0; r < 4; r++)
#pragma unroll
      for (int j = 0; j < 8; j++)
        __hip_atomic_fetch_add(Cp + (size_t)r * CC + j, acc[r * 8 + j],
                               __ATOMIC_RELAXED, __HIP_MEMORY_SCOPE_AGENT);
  }
}

// Sequential step t: logit = Wv[:,t] + (t? U@r_{t-1} + b_h : b_init); sample.
// block 256 = b(32) x ks(4) x r(2); 2 rows/block; grid 512.
__global__ __launch_bounds__(256)
void step1(const float* __restrict__ U, const float* __restrict__ rt,
           const double* __restrict__ Wv,
           const float* __restrict__ b_h, const float* __restrict__ b_init,
           float* __restrict__ h_all, int t, uint32_t key0, uint32_t key1) {
  __shared__ double red[2][3][32];
  int tid = threadIdx.x;
  int b = tid & 31, ks = (tid >> 5) & 3, r = tid >> 7;
  int n = blockIdx.x * 2 + r;

  double a0 = 0, a1 = 0, a2 = 0, a3 = 0;
  if (t > 0) {
    const float* urow = U + (size_t)n * NHH;
    const float* xp = rt + (long)(t - 1) * 32 + b;
    int kbeg = ks * 256;
    for (int k = kbeg; k < kbeg + 256; k += 4) {
      float4 uq = *(const float4*)(urow + k);
      float x0 = xp[(size_t)k * CC], x1 = xp[(size_t)(k + 1) * CC];
      float x2 = xp[(size_t)(k + 2) * CC], x3 = xp[(size_t)(k + 3) * CC];
      a0 += (double)uq.x * (double)x0;
      a1 += (double)uq.y * (double)x1;
      a2 += (double)uq.z * (double)x2;
      a3 += (double)uq.w * (double)x3;
    }
  }
  double part = (a0 + a1) + (a2 + a3);
  if (ks > 0) red[r][ks - 1][b] = part;
  __syncthreads();
  if (ks == 0) {
    double s = part + red[r][0][b] + red[r][1][b] + red[r][2][b];
    double hbv = (t > 0) ? (s + (double)b_h[n]) : (double)b_init[n];
    double logit = Wv[(size_t)n * CC + t * 32 + b] + hbv;
    float p32, bit;
    bern_sample(logit, key0, key1, (uint32_t)(n * 32 + b), p32, bit);
    // rt (means, the recurrence + output) and h bits (staged in rmodel region)
    ((float*)rt)[(size_t)n * CC + t * 32 + b] = p32;
    h_all[(size_t)n * CC + t * 32 + b] = bit;
  }
}

// Batched W^T phases (2 & 4): bit[i][c] = bern(sigma(sum_k W[k][i] x[k][c] + b_v[i]))
// block 256 = cthr(32) x rg(8); 32 rows x 256 cols; full K=1024; grid 1024.
__global__ __launch_bounds__(256, 3)
void gemmT_sample(const float* __restrict__ W, const float* __restrict__ x,
                  const float* __restrict__ b_v, float* __restrict__ dst,
                  int phase, uint32_t rk00, uint32_t rk01, uint32_t rk10, uint32_t rk11) {
  int tid = threadIdx.x;
  int cthr = tid & 31;
  int rg = tid >> 5;
  int ib = blockIdx.x >> 3, cb = blockIdx.x & 7;
  int i0 = ib * 32 + rg * 4;
  int c0 = cb * 256 + cthr * 8;

  double acc[32];
#pragma unroll
  for (int q = 0; q < 32; q++) acc[q] = 0.0;

  for (int k = 0; k < NHH; k += 4) {
#pragma unroll
    for (int kk = 0; kk < 4; kk++) {
      const float* xp = x + (size_t)(k + kk) * CC + c0;
      float4 xlo = *(const float4*)(xp);
      float4 xhi = *(const float4*)(xp + 4);
      float4 w = *(const float4*)(W + (size_t)(k + kk) * NVV + i0);
      double xd[8] = {xlo.x, xlo.y, xlo.z, xlo.w, xhi.x, xhi.y, xhi.z, xhi.w};
      double wd[4] = {w.x, w.y, w.z, w.w};
#pragma unroll
      for (int r = 0; r < 4; r++)
#pragma unroll
        for (int j = 0; j < 8; j++) acc[r * 8 + j] += wd[r] * xd[j];
    }
  }

  int t = c0 >> 5;
  uint32_t ck0, ck1;
  step_key(t, phase, rk00, rk01, rk10, rk11, ck0, ck1);
#pragma unroll
  for (int r = 0; r < 4; r++) {
    int i = i0 + r;
    double bv = (double)b_v[i];
#pragma unroll
    for (int j = 0; j < 8; j++) {
      int c = c0 + j, b = c & 31;
      float p32, bit;
      bern_sample(acc[r * 8 + j] + bv, ck0, ck1, (uint32_t)(i * 32 + b), p32, bit);
      (void)p32;
      dst[(size_t)i * CC + c] = bit;
    }
  }
}

// Stage 3 epilogue: logit = buf[n][c] + (t? b_h[n] : b_init[n]); sample h2 -> rmodel.
__global__ void bias_sig_sample(const double* __restrict__ buf,
                                const float* __restrict__ b_h,
                                const float* __restrict__ b_init,
                                float* __restrict__ rmodel,
                                uint32_t rk00, uint32_t rk01, uint32_t rk10, uint32_t rk11) {
  int idx = blockIdx.x * 256 + threadIdx.x;   // over 1024*2048
  int n = idx >> 11, c = idx & 2047;
  int t = c >> 5, b = c & 31;
  uint32_t ck0, ck1;
  step_key(t, 2, rk00, rk01, rk10, rk11, ck0, ck1);
  double bias = (t > 0) ? (double)b_h[n] : (double)b_init[n];
  float p32, bit;
  bern_sample(buf[idx] + bias, ck0, ck1, (uint32_t)(n * 32 + b), p32, bit);
  (void)p32;
  rmodel[idx] = bit;
}

// ---------------------------------------------------------------------------
static void tf_split(const uint32_t key[2], int n, uint32_t out[][2]) {
  for (int i = 0; i < n; i++)
    tf2x32(key[0], key[1], 0u, (uint32_t)i, out[i][0], out[i][1]);
}

extern "C" void kernel_launch(void* const* d_in, const int* in_sizes, int n_in,
                              void* d_out, int out_size, void* d_ws, size_t ws_size,
                              hipStream_t stream) {
  const float* v      = (const float*)d_in[0];   // [NVV][TT][BB] = [4096][2048]
  const float* W      = (const float*)d_in[1];   // [NHH][NVV]
  const float* U      = (const float*)d_in[2];   // [NHH][NHH]
  const float* b_v    = (const float*)d_in[3];
  const float* b_h    = (const float*)d_in[4];
  const float* b_init = (const float*)d_in[5];

  float* out    = (float*)d_out;
  float* vmodel = out;                           // [NVV][CC]  (hosts vm, then final)
  float* rmodel = out + (size_t)NVV * CC;        // [NHH][CC]  (hosts h bits, then h2)
  float* rt     = rmodel + (size_t)NHH * CC;     // [NHH][CC]  (p means, recurrence)

  double* Wv = (double*)d_ws;                    // [NHH][CC] f64 = 16 MiB scratch

  // key tree: key(42)->(k0,ks); t=0: split(k0,4); t>0: split(split(ks,63)[t-1],4)
  uint32_t root[2] = {0u, 42u};
  uint32_t rk[2][2];  tf_split(root, 2, rk);
  uint32_t tk[63][2]; tf_split(rk[1], 63, tk);

  // Stage 0: Wv = W @ v  (all timesteps, parallel)
  hipLaunchKernelGGL(zfill, dim3(8192), dim3(256), 0, stream, Wv, NHH * CC);
  hipLaunchKernelGGL(gemm_acc, dim3(1024), dim3(256), 0, stream,
                     W, NVV, v, Wv, NVV, 0);

  // Stage 1: sequential recurrence (the only serial part)
  for (int t = 0; t < TT; t++) {
    uint32_t key_t0 = t ? tk[t - 1][0] : rk[0][0];
    uint32_t key_t1 = t ? tk[t - 1][1] : rk[0][1];
    uint32_t ck0, ck1;
    tf2x32(key_t0, key_t1, 0u, 0u, ck0, ck1);   // split(key_t,4)[0]
    hipLaunchKernelGGL(step1, dim3(512), dim3(256), 0, stream,
                       U, rt, Wv, b_h, b_init, rmodel /* h bits staging */,
                       t, ck0, ck1);
  }

  // Stage 2: vm = bern(sigma(W^T @ h + b_v))  for all t -> vmodel region
  hipLaunchKernelGGL(gemmT_sample, dim3(1024), dim3(256), 0, stream,
                     W, rmodel /* h bits */, b_v, vmodel, 1,
                     rk[0][0], rk[0][1], rk[1][0], rk[1][1]);

  // Stage 3: h2 = bern(sigma(W @ vm + U @ r_shift + bias)) -> rmodel
  hipLaunchKernelGGL(zfill, dim3(8192), dim3(256), 0, stream, Wv, NHH * CC);
  hipLaunchKernelGGL(gemm_acc, dim3(1024), dim3(256), 0, stream,
                     W, NVV, vmodel /* vm bits */, Wv, NVV, 0);
  hipLaunchKernelGGL(gemm_acc, dim3(1024), dim3(256), 0, stream,
                     U, NHH, rt - 32 /* r shifted one step */, Wv, NHH, 1);
  hipLaunchKernelGGL(bias_sig_sample, dim3(8192), dim3(256), 0, stream,
                     Wv, b_h, b_init, rmodel,
                     rk[0][0], rk[0][1], rk[1][0], rk[1][1]);

  // Stage 4: v_model = bern(sigma(W^T @ h2 + b_v)) -> vmodel (final)
  hipLaunchKernelGGL(gemmT_sample, dim3(1024), dim3(256), 0, stream,
                     W, rmodel /* h2 bits */, b_v, vmodel, 3,
                     rk[0][0], rk[0][1], rk[1][0], rk[1][1]);

  (void)in_sizes; (void)n_in; (void)out_size; (void)ws_size;
}

// Round 4
// 2053.723 us; speedup vs baseline: 5.9971x; 2.2662x over previous
//
#include <hip/hip_runtime.h>
#include <cstdint>
#include <cstddef>
#include <math.h>

// ---------------------------------------------------------------------------
// RTRBM forward, CD-2 Gibbs, bit-exact JAX threefry (partitionable mode).
// Round 4: exact fixed-point i8-MFMA GEMMs. W,U sliced to 6 signed-i8 planes
// (scale 2^-48), r to 5 planes (scale 2^-38); activations are 0/1 bytes.
// i32 MFMA accumulation is exact; fp64 recombination error <= ~7e-12 —
// far below every Bernoulli margin. Serial part: 64 tiny step1 launches.
// ---------------------------------------------------------------------------

#define NVV 4096
#define NHH 1024
#define TT  64
#define BB  32
#define CC  2048

typedef int v4i  __attribute__((ext_vector_type(4)));
typedef int v16i __attribute__((ext_vector_type(16)));

__constant__ double SC6[6] = {0x1p-48, 0x1p-40, 0x1p-32, 0x1p-24, 0x1p-16, 0x1p-8};
__constant__ double PSC[10] = {0, 0, 0, 0x1p-62, 0x1p-54, 0x1p-46,
                               0x1p-38, 0x1p-30, 0x1p-22, 0x1p-14};

__host__ __device__ __forceinline__ void tf2x32(uint32_t k0, uint32_t k1,
                                                uint32_t x0, uint32_t x1,
                                                uint32_t& o0, uint32_t& o1) {
  uint32_t ks2 = k0 ^ k1 ^ 0x1BD11BDAu;
#define TF_RND(r) { x0 += x1; x1 = (x1 << (r)) | (x1 >> (32 - (r))); x1 ^= x0; }
  x0 += k0; x1 += k1;
  TF_RND(13) TF_RND(15) TF_RND(26) TF_RND(6)
  x0 += k1;  x1 += ks2 + 1u;
  TF_RND(17) TF_RND(29) TF_RND(16) TF_RND(24)
  x0 += ks2; x1 += k0 + 2u;
  TF_RND(13) TF_RND(15) TF_RND(26) TF_RND(6)
  x0 += k0;  x1 += k1 + 3u;
  TF_RND(17) TF_RND(29) TF_RND(16) TF_RND(24)
  x0 += k1;  x1 += ks2 + 4u;
  TF_RND(13) TF_RND(15) TF_RND(26) TF_RND(6)
  x0 += ks2; x1 += k0 + 5u;
#undef TF_RND
  o0 = x0; o1 = x1;
}

__device__ __forceinline__ float tf_uniform(uint32_t k0, uint32_t k1, uint32_t j) {
  uint32_t o0, o1;
  tf2x32(k0, k1, 0u, j, o0, o1);
  uint32_t bits = o0 ^ o1;
  return __uint_as_float((bits >> 9) | 0x3f800000u) - 1.0f;
}

__device__ __forceinline__ void bern_sample(double logit, uint32_t k0, uint32_t k1,
                                            uint32_t j, float& p32, float& bit) {
  double pd = 1.0 / (1.0 + exp(-logit));
  p32 = (float)pd;
  float u = tf_uniform(k0, k1, j);
  bit = (u < p32) ? 1.0f : 0.0f;
}

__device__ __forceinline__ void step_key(int t, int phase,
                                         uint32_t rk00, uint32_t rk01,
                                         uint32_t rk10, uint32_t rk11,
                                         uint32_t& c0, uint32_t& c1) {
  uint32_t kt0, kt1;
  tf2x32(rk10, rk11, 0u, (uint32_t)(t > 0 ? t - 1 : 0), kt0, kt1);
  if (t == 0) { kt0 = rk00; kt1 = rk01; }
  tf2x32(kt0, kt1, 0u, (uint32_t)phase, c0, c1);
}

__device__ __forceinline__ void slice6(float w, signed char sb[6]) {
  long long v = __double2ll_rn((double)w * 0x1p48);
#pragma unroll
  for (int s = 0; s < 6; s++) {
    signed char b = (signed char)(v & 0xFF);
    sb[s] = b;
    v = (v - b) >> 8;
  }
}

__device__ __forceinline__ void slice5(float r, signed char sb[5]) {
  long long v = __double2ll_rn((double)r * 0x1p38);
#pragma unroll
  for (int s = 0; s < 5; s++) {
    signed char b = (signed char)(v & 0xFF);
    sb[s] = b;
    v = (v - b) >> 8;
  }
}

// ---------------------------------------------------------------------------
// Prep: W [1024][4096] f32 -> Ws[6][1024][4096] i8 and WsT[6][4096][1024] i8
__global__ __launch_bounds__(256)
void prepW(const float* __restrict__ W, signed char* __restrict__ Ws,
           signed char* __restrict__ WsT) {
  __shared__ float tl[64][65];
  int bi = blockIdx.x >> 6;   // n-tile 0..15
  int bj = blockIdx.x & 63;   // k-tile 0..63
  int n0 = bi * 64, k0 = bj * 64;
  int tid = threadIdx.x;
#pragma unroll
  for (int it = 0; it < 4; it++) {
    int r = (tid >> 4) + it * 16, c4 = (tid & 15) * 4;
    float4 q = *(const float4*)(W + (size_t)(n0 + r) * NVV + k0 + c4);
    tl[r][c4] = q.x; tl[r][c4 + 1] = q.y; tl[r][c4 + 2] = q.z; tl[r][c4 + 3] = q.w;
  }
  __syncthreads();
#pragma unroll
  for (int it = 0; it < 4; it++) {
    int r = (tid >> 4) + it * 16, c4 = (tid & 15) * 4;
    unsigned int pk[6] = {0, 0, 0, 0, 0, 0};
    for (int j = 0; j < 4; j++) {
      signed char sb[6]; slice6(tl[r][c4 + j], sb);
      for (int s = 0; s < 6; s++) pk[s] |= ((unsigned)(unsigned char)sb[s]) << (8 * j);
    }
    for (int s = 0; s < 6; s++)
      *(unsigned int*)(Ws + (size_t)s * NHH * NVV + (size_t)(n0 + r) * NVV + k0 + c4) = pk[s];
  }
#pragma unroll
  for (int it = 0; it < 4; it++) {
    int r = (tid >> 4) + it * 16, c4 = (tid & 15) * 4;  // r = i-local, c4 = n-quad
    unsigned int pk[6] = {0, 0, 0, 0, 0, 0};
    for (int j = 0; j < 4; j++) {
      signed char sb[6]; slice6(tl[c4 + j][r], sb);
      for (int s = 0; s < 6; s++) pk[s] |= ((unsigned)(unsigned char)sb[s]) << (8 * j);
    }
    for (int s = 0; s < 6; s++)
      *(unsigned int*)(WsT + (size_t)s * NVV * NHH + (size_t)(k0 + r) * NHH + n0 + c4) = pk[s];
  }
}

// Prep: U [1024][1024] -> Us[6][1024][1024] (row-major only)
__global__ __launch_bounds__(256)
void prepU(const float* __restrict__ U, signed char* __restrict__ Us) {
  int idx = blockIdx.x * 256 + threadIdx.x;  // 262144
  int n = idx >> 8, k4 = (idx & 255) * 4;
  float4 q = *(const float4*)(U + (size_t)n * NHH + k4);
  float w[4] = {q.x, q.y, q.z, q.w};
  unsigned int pk[6] = {0, 0, 0, 0, 0, 0};
  for (int j = 0; j < 4; j++) {
    signed char sb[6]; slice6(w[j], sb);
    for (int s = 0; s < 6; s++) pk[s] |= ((unsigned)(unsigned char)sb[s]) << (8 * j);
  }
  for (int s = 0; s < 6; s++)
    *(unsigned int*)(Us + (size_t)s * NHH * NHH + (size_t)n * NHH + k4) = pk[s];
}

// Prep: v [4096][2048] f32 bits -> vT [2048][4096] i8
__global__ __launch_bounds__(256)
void prepVT(const float* __restrict__ v, signed char* __restrict__ vT) {
  __shared__ float tl[64][65];
  int bi = blockIdx.x >> 5;  // i-tile 0..63
  int bj = blockIdx.x & 31;  // c-tile 0..31
  int i0 = bi * 64, c0 = bj * 64;
  int tid = threadIdx.x;
#pragma unroll
  for (int it = 0; it < 4; it++) {
    int r = (tid >> 4) + it * 16, c4 = (tid & 15) * 4;
    float4 q = *(const float4*)(v + (size_t)(i0 + r) * CC + c0 + c4);
    tl[r][c4] = q.x; tl[r][c4 + 1] = q.y; tl[r][c4 + 2] = q.z; tl[r][c4 + 3] = q.w;
  }
  __syncthreads();
#pragma unroll
  for (int it = 0; it < 4; it++) {
    int cc = (tid >> 4) + it * 16, i4 = (tid & 15) * 4;
    unsigned int pk = 0;
    for (int j = 0; j < 4; j++)
      pk |= ((unsigned)(tl[i4 + j][cc] != 0.0f ? 1 : 0)) << (8 * j);
    *(unsigned int*)(vT + (size_t)(c0 + cc) * NVV + i0 + i4) = pk;
  }
}

// Prep: rt [1024][2048] -> rTq[5][2048][1024], shifted +32 cols (r_lag)
__global__ __launch_bounds__(256)
void sliceR(const float* __restrict__ rt, signed char* __restrict__ rTq) {
  __shared__ float tl[64][65];
  int bi = blockIdx.x >> 5;  // n-tile 0..15
  int bj = blockIdx.x & 31;  // c-tile 0..31
  int n0 = bi * 64, c0 = bj * 64;
  int tid = threadIdx.x;
#pragma unroll
  for (int it = 0; it < 4; it++) {
    int r = (tid >> 4) + it * 16, c4 = (tid & 15) * 4;
    float4 q = *(const float4*)(rt + (size_t)(n0 + r) * CC + c0 + c4);
    tl[r][c4] = q.x; tl[r][c4 + 1] = q.y; tl[r][c4 + 2] = q.z; tl[r][c4 + 3] = q.w;
  }
  __syncthreads();
#pragma unroll
  for (int it = 0; it < 4; it++) {
    int cc = (tid >> 4) + it * 16, n4 = (tid & 15) * 4;
    int cg = c0 + cc;
    if (cg < CC - 32) {
      unsigned int pk[5] = {0, 0, 0, 0, 0};
      for (int j = 0; j < 4; j++) {
        signed char sb[5]; slice5(tl[n4 + j][cc], sb);
        for (int q = 0; q < 5; q++) pk[q] |= ((unsigned)(unsigned char)sb[q]) << (8 * j);
      }
      for (int q = 0; q < 5; q++)
        *(unsigned int*)(rTq + (size_t)q * CC * NHH + (size_t)(cg + 32) * NHH + n0 + n4) = pk[q];
    }
  }
}

// ---------------------------------------------------------------------------
// Stage 0: WvT[c][n] f64 = (vT @ Ws^T) * 2^-48.  M=2048(c) N=1024(n) K=4096.
__global__ __launch_bounds__(256, 2)
void s0k(const signed char* __restrict__ vT, const signed char* __restrict__ Ws,
         double* __restrict__ WvT) {
  int wave = threadIdx.x >> 6, lane = threadIdx.x & 63;
  int lrow = lane & 31, lhalf = lane >> 5;
  int bm = blockIdx.x >> 4, bn = blockIdx.x & 15;
  int m0 = bm * 64 + (wave & 1) * 32;
  int n0 = bn * 64 + (wave >> 1) * 32;

  v16i acc[6];
  for (int s = 0; s < 6; s++) for (int e = 0; e < 16; e++) acc[s][e] = 0;

  const signed char* aB = vT + (size_t)(m0 + lrow) * NVV + 16 * lhalf;
  const signed char* bB = Ws + (size_t)(n0 + lrow) * NVV + 16 * lhalf;
#pragma unroll 2
  for (int kb = 0; kb < NVV; kb += 32) {
    v4i af = *(const v4i*)(aB + kb);
#pragma unroll
    for (int s = 0; s < 6; s++) {
      v4i bf = *(const v4i*)(bB + (size_t)s * NHH * NVV + kb);
      acc[s] = __builtin_amdgcn_mfma_i32_32x32x32_i8(af, bf, acc[s], 0, 0, 0);
    }
  }
#pragma unroll
  for (int e = 0; e < 16; e++) {
    int row = (e & 3) + 8 * (e >> 2) + 4 * lhalf;
    double lg = 0;
    for (int s = 0; s < 6; s++) lg += (double)acc[s][e] * SC6[s];
    WvT[(size_t)(m0 + row) * NHH + n0 + lrow] = lg;
  }
}

// Serial step t: logit = WvT + (t? U@r_lag + b_h : b_init); sample h, r.
__global__ __launch_bounds__(256)
void step1(const float* __restrict__ U, const float* __restrict__ rin,
           float* __restrict__ rout, const double* __restrict__ WvT,
           const float* __restrict__ b_h, const float* __restrict__ b_init,
           float* __restrict__ rt, unsigned char* __restrict__ hT,
           int t, uint32_t key0, uint32_t key1) {
  __shared__ double red[2][4][32];
  int tid = threadIdx.x;
  int b = tid & 31, ks = (tid >> 5) & 3, rr = tid >> 7;
  int n = blockIdx.x * 2 + rr;
  double a0 = 0, a1 = 0, a2 = 0, a3 = 0;
  if (t > 0) {
    const float* urow = U + (size_t)n * NHH + ks * 256;
    const float* rp = rin + b;
    for (int k = 0; k < 256; k += 4) {
      float4 uq = *(const float4*)(urow + k);
      int kk = (ks * 256 + k) * 32;
      a0 += (double)uq.x * (double)rp[kk];
      a1 += (double)uq.y * (double)rp[kk + 32];
      a2 += (double)uq.z * (double)rp[kk + 64];
      a3 += (double)uq.w * (double)rp[kk + 96];
    }
  }
  red[rr][ks][b] = (a0 + a1) + (a2 + a3);
  __syncthreads();
  if (ks == 0) {
    double s = red[rr][0][b] + red[rr][1][b] + red[rr][2][b] + red[rr][3][b];
    double wv = WvT[(size_t)(t * 32 + b) * NHH + n];
    double lg = (t > 0) ? (wv + s + (double)b_h[n]) : (wv + (double)b_init[n]);
    float p32, bit;
    bern_sample(lg, key0, key1, (uint32_t)(n * 32 + b), p32, bit);
    rt[(size_t)n * CC + t * 32 + b] = p32;
    rout[n * 32 + b] = p32;
    hT[(size_t)(t * 32 + b) * NHH + n] = (unsigned char)(bit != 0.0f ? 1 : 0);
  }
}

// Stages 2/4: out[i][c] = bern(sigma(W^T@x + b_v)). A=WsT(6) B=xT(bits). K=1024.
__global__ __launch_bounds__(256, 2)
void sV(const signed char* __restrict__ WsT, const signed char* __restrict__ xT,
        const float* __restrict__ b_v, unsigned char* __restrict__ bitT,
        float* __restrict__ f32out, int phase,
        uint32_t rk00, uint32_t rk01, uint32_t rk10, uint32_t rk11) {
  __shared__ float tile[4][32][36];
  int wave = threadIdx.x >> 6, lane = threadIdx.x & 63;
  int lrow = lane & 31, lhalf = lane >> 5;
  int bm = blockIdx.x >> 5, bn = blockIdx.x & 31;
  int m0 = bm * 64 + (wave & 1) * 32;   // i
  int n0 = bn * 64 + (wave >> 1) * 32;  // c

  v16i acc[6];
  for (int s = 0; s < 6; s++) for (int e = 0; e < 16; e++) acc[s][e] = 0;

  const signed char* aB = WsT + (size_t)(m0 + lrow) * NHH + 16 * lhalf;
  const signed char* bB = xT + (size_t)(n0 + lrow) * NHH + 16 * lhalf;
#pragma unroll 2
  for (int kb = 0; kb < NHH; kb += 32) {
    v4i bf = *(const v4i*)(bB + kb);
#pragma unroll
    for (int s = 0; s < 6; s++) {
      v4i af = *(const v4i*)(aB + (size_t)s * NVV * NHH + kb);
      acc[s] = __builtin_amdgcn_mfma_i32_32x32x32_i8(af, bf, acc[s], 0, 0, 0);
    }
  }

  int t = n0 >> 5;
  uint32_t ck0, ck1;
  step_key(t, phase, rk00, rk01, rk10, rk11, ck0, ck1);

  float bits[16];
#pragma unroll
  for (int g = 0; g < 4; g++) {
    unsigned int packed = 0;
#pragma unroll
    for (int q = 0; q < 4; q++) {
      int e = g * 4 + q;
      int row = q + 8 * g + 4 * lhalf;
      int i = m0 + row;
      double lg = (double)b_v[i];
      for (int s = 0; s < 6; s++) lg += (double)acc[s][e] * SC6[s];
      float p32, bit;
      bern_sample(lg, ck0, ck1, (uint32_t)(i * 32 + lrow), p32, bit);
      (void)p32;
      bits[e] = bit;
      packed |= ((unsigned)(bit != 0.0f ? 1 : 0)) << (8 * q);
    }
    if (bitT)
      *(unsigned int*)(bitT + (size_t)(n0 + lrow) * NVV + m0 + 8 * g + 4 * lhalf) = packed;
  }

  if (f32out) {
#pragma unroll
    for (int e = 0; e < 16; e++) {
      int row = (e & 3) + 8 * (e >> 2) + 4 * lhalf;
      tile[wave][row][lrow] = bits[e];
    }
    __syncthreads();
    int rr = lane >> 1, hf = lane & 1;
#pragma unroll
    for (int j4 = 0; j4 < 4; j4++) {
      float4 o = *(const float4*)&tile[wave][rr][hf * 16 + j4 * 4];
      *(float4*)(f32out + (size_t)(m0 + rr) * CC + n0 + hf * 16 + j4 * 4) = o;
    }
  }
}

// Stage 3: logit = W@vm + U@r_lag + bias; sample h2 -> h2T + rmodel.
// M=2048(c) N=1024(n). Phase 1: A=vmT(1) B=Ws(6) K=4096. Phase 2: pairs.
__global__ __launch_bounds__(256, 2)
void s3k(const signed char* __restrict__ vmT, const signed char* __restrict__ Ws,
         const signed char* __restrict__ rTq, const signed char* __restrict__ Us,
         const float* __restrict__ b_h, const float* __restrict__ b_init,
         unsigned char* __restrict__ h2T, float* __restrict__ rmodel,
         uint32_t rk00, uint32_t rk01, uint32_t rk10, uint32_t rk11) {
  int wave = threadIdx.x >> 6, lane = threadIdx.x & 63;
  int lrow = lane & 31, lhalf = lane >> 5;
  int bm = blockIdx.x >> 4, bn = blockIdx.x & 15;
  int m0 = bm * 64 + (wave & 1) * 32;   // c
  int n0 = bn * 64 + (wave >> 1) * 32;  // n

  double lg[16];
  {
    v16i acc[6];
    for (int s = 0; s < 6; s++) for (int e = 0; e < 16; e++) acc[s][e] = 0;
    const signed char* aB = vmT + (size_t)(m0 + lrow) * NVV + 16 * lhalf;
    const signed char* bB = Ws + (size_t)(n0 + lrow) * NVV + 16 * lhalf;
#pragma unroll 2
    for (int kb = 0; kb < NVV; kb += 32) {
      v4i af = *(const v4i*)(aB + kb);
#pragma unroll
      for (int s = 0; s < 6; s++) {
        v4i bf = *(const v4i*)(bB + (size_t)s * NHH * NVV + kb);
        acc[s] = __builtin_amdgcn_mfma_i32_32x32x32_i8(af, bf, acc[s], 0, 0, 0);
      }
    }
#pragma unroll
    for (int e = 0; e < 16; e++) {
      double v = 0;
      for (int s = 0; s < 6; s++) v += (double)acc[s][e] * SC6[s];
      lg[e] = v;
    }
  }
  // U @ r_lag slice pairs (q: r slices scale 2^-38; s: U slices scale 2^-48)
  for (int q = 0; q < 5; q++) {
    const signed char* ap = rTq + (size_t)q * CC * NHH + (size_t)(m0 + lrow) * NHH + 16 * lhalf;
    for (int s = 0; s < 6; s++) {
      if (q + s < 3) continue;
      const signed char* bp = Us + (size_t)s * NHH * NHH + (size_t)(n0 + lrow) * NHH + 16 * lhalf;
      v16i a1;
      for (int e = 0; e < 16; e++) a1[e] = 0;
#pragma unroll 2
      for (int kb = 0; kb < NHH; kb += 32)
        a1 = __builtin_amdgcn_mfma_i32_32x32x32_i8(*(const v4i*)(ap + kb),
                                                   *(const v4i*)(bp + kb), a1, 0, 0, 0);
      double psc = PSC[q + s];
#pragma unroll
      for (int e = 0; e < 16; e++) lg[e] += (double)a1[e] * psc;
    }
  }

  int t = m0 >> 5;
  uint32_t ck0, ck1;
  step_key(t, 2, rk00, rk01, rk10, rk11, ck0, ck1);
  int n = n0 + lrow;
  double bias = (t > 0) ? (double)b_h[n] : (double)b_init[n];
#pragma unroll
  for (int e = 0; e < 16; e++) {
    int row = (e & 3) + 8 * (e >> 2) + 4 * lhalf;
    int c = m0 + row;
    float p32, bit;
    bern_sample(lg[e] + bias, ck0, ck1, (uint32_t)(n * 32 + row), p32, bit);
    (void)p32;
    h2T[(size_t)c * NHH + n] = (unsigned char)(bit != 0.0f ? 1 : 0);
    rmodel[(size_t)n * CC + c] = bit;
  }
}

// ---------------------------------------------------------------------------
static void tf_split(const uint32_t key[2], int n, uint32_t out[][2]) {
  for (int i = 0; i < n; i++)
    tf2x32(key[0], key[1], 0u, (uint32_t)i, out[i][0], out[i][1]);
}

extern "C" void kernel_launch(void* const* d_in, const int* in_sizes, int n_in,
                              void* d_out, int out_size, void* d_ws, size_t ws_size,
                              hipStream_t stream) {
  const float* v      = (const float*)d_in[0];
  const float* W      = (const float*)d_in[1];
  const float* U      = (const float*)d_in[2];
  const float* b_v    = (const float*)d_in[3];
  const float* b_h    = (const float*)d_in[4];
  const float* b_init = (const float*)d_in[5];

  float* out    = (float*)d_out;
  float* vmodel = out;                           // [4096][2048]
  float* rmodel = out + (size_t)NVV * CC;        // [1024][2048]
  float* rt     = rmodel + (size_t)NHH * CC;     // [1024][2048]

  char* wsb = (char*)d_ws;
  signed char* Ws   = (signed char*)wsb;                         // 24 MB
  signed char* WsT  = (signed char*)(wsb + 25165824);            // 24 MB
  signed char* Us   = (signed char*)(wsb + 50331648);            // 6 MB
  signed char* vT   = (signed char*)(wsb + 56623104);            // 8 MB
  unsigned char* hT = (unsigned char*)(wsb + 65011712);          // 2 MB
  signed char* vmT  = (signed char*)(wsb + 67108864);            // 8 MB
  unsigned char* h2T= (unsigned char*)(wsb + 75497472);          // 2 MB
  signed char* rTq  = (signed char*)(wsb + 77594624);            // 10 MB
  double* WvT       = (double*)(wsb + 88080384);                 // 16 MB
  float* r_cmp      = (float*)(wsb + 104857600);                 // 2 x 128 KB

  uint32_t root[2] = {0u, 42u};
  uint32_t rk[2][2];  tf_split(root, 2, rk);
  uint32_t tk[63][2]; tf_split(rk[1], 63, tk);

  // --- prep ---
  hipLaunchKernelGGL(prepW, dim3(1024), dim3(256), 0, stream, W, Ws, WsT);
  hipLaunchKernelGGL(prepU, dim3(1024), dim3(256), 0, stream, U, Us);
  hipLaunchKernelGGL(prepVT, dim3(2048), dim3(256), 0, stream, v, vT);
  hipMemsetAsync(rTq, 0, (size_t)5 * CC * NHH, stream);

  // --- stage 0: WvT = W@v (all t) ---
  hipLaunchKernelGGL(s0k, dim3(512), dim3(256), 0, stream, vT, Ws, WvT);

  // --- stage 1: serial recurrence ---
  for (int t = 0; t < TT; t++) {
    uint32_t key_t0 = t ? tk[t - 1][0] : rk[0][0];
    uint32_t key_t1 = t ? tk[t - 1][1] : rk[0][1];
    uint32_t ck0, ck1;
    tf2x32(key_t0, key_t1, 0u, 0u, ck0, ck1);
    float* rin  = r_cmp + ((t + 1) & 1) * 32768;
    float* rout = r_cmp + (t & 1) * 32768;
    hipLaunchKernelGGL(step1, dim3(512), dim3(256), 0, stream,
                       U, rin, rout, WvT, b_h, b_init, rt, hT, t, ck0, ck1);
  }
  hipLaunchKernelGGL(sliceR, dim3(512), dim3(256), 0, stream, rt, rTq);

  // --- stage 2: vm bits ---
  hipLaunchKernelGGL(sV, dim3(2048), dim3(256), 0, stream,
                     WsT, (const signed char*)hT, b_v, (unsigned char*)vmT,
                     (float*)nullptr, 1, rk[0][0], rk[0][1], rk[1][0], rk[1][1]);

  // --- stage 3: h2 bits + rmodel ---
  hipLaunchKernelGGL(s3k, dim3(512), dim3(256), 0, stream,
                     vmT, Ws, rTq, Us, b_h, b_init, h2T, rmodel,
                     rk[0][0], rk[0][1], rk[1][0], rk[1][1]);

  // --- stage 4: vmodel ---
  hipLaunchKernelGGL(sV, dim3(2048), dim3(256), 0, stream,
                     WsT, (const signed char*)h2T, b_v, (unsigned char*)nullptr,
                     vmodel, 3, rk[0][0], rk[0][1], rk[1][0], rk[1][1]);

  (void)in_sizes; (void)n_in; (void)out_size; (void)ws_size;
}

// Round 5
// 1346.460 us; speedup vs baseline: 9.1473x; 1.5253x over previous
//
#include <hip/hip_runtime.h>
#include <cstdint>
#include <cstddef>
#include <math.h>

// ---------------------------------------------------------------------------
// RTRBM forward, CD-2 Gibbs, bit-exact JAX threefry (partitionable mode).
// Round 5: (1) stage-3 reuses fp64 hid_bias computed by step1 (removes the
// 24 U@r slice-pair GEMMs), (2) 64x32 wave tiles share the 6-slice operand
// across 2 MFMA tiles (halves bytes/MFMA), (3) XCD-aware block swizzle keeps
// each XCD's slice working set in its 4 MB L2.
// i8 MFMA accumulation exact; fp64 recombination err <= ~7e-12.
// ---------------------------------------------------------------------------

#define NVV 4096
#define NHH 1024
#define TT  64
#define BB  32
#define CC  2048

typedef int v4i  __attribute__((ext_vector_type(4)));
typedef int v16i __attribute__((ext_vector_type(16)));

__constant__ double SC6[6] = {0x1p-48, 0x1p-40, 0x1p-32, 0x1p-24, 0x1p-16, 0x1p-8};

__host__ __device__ __forceinline__ void tf2x32(uint32_t k0, uint32_t k1,
                                                uint32_t x0, uint32_t x1,
                                                uint32_t& o0, uint32_t& o1) {
  uint32_t ks2 = k0 ^ k1 ^ 0x1BD11BDAu;
#define TF_RND(r) { x0 += x1; x1 = (x1 << (r)) | (x1 >> (32 - (r))); x1 ^= x0; }
  x0 += k0; x1 += k1;
  TF_RND(13) TF_RND(15) TF_RND(26) TF_RND(6)
  x0 += k1;  x1 += ks2 + 1u;
  TF_RND(17) TF_RND(29) TF_RND(16) TF_RND(24)
  x0 += ks2; x1 += k0 + 2u;
  TF_RND(13) TF_RND(15) TF_RND(26) TF_RND(6)
  x0 += k0;  x1 += k1 + 3u;
  TF_RND(17) TF_RND(29) TF_RND(16) TF_RND(24)
  x0 += k1;  x1 += ks2 + 4u;
  TF_RND(13) TF_RND(15) TF_RND(26) TF_RND(6)
  x0 += ks2; x1 += k0 + 5u;
#undef TF_RND
  o0 = x0; o1 = x1;
}

__device__ __forceinline__ float tf_uniform(uint32_t k0, uint32_t k1, uint32_t j) {
  uint32_t o0, o1;
  tf2x32(k0, k1, 0u, j, o0, o1);
  uint32_t bits = o0 ^ o1;
  return __uint_as_float((bits >> 9) | 0x3f800000u) - 1.0f;
}

__device__ __forceinline__ void bern_sample(double logit, uint32_t k0, uint32_t k1,
                                            uint32_t j, float& p32, float& bit) {
  double pd = 1.0 / (1.0 + exp(-logit));
  p32 = (float)pd;
  float u = tf_uniform(k0, k1, j);
  bit = (u < p32) ? 1.0f : 0.0f;
}

__device__ __forceinline__ void step_key(int t, int phase,
                                         uint32_t rk00, uint32_t rk01,
                                         uint32_t rk10, uint32_t rk11,
                                         uint32_t& c0, uint32_t& c1) {
  uint32_t kt0, kt1;
  tf2x32(rk10, rk11, 0u, (uint32_t)(t > 0 ? t - 1 : 0), kt0, kt1);
  if (t == 0) { kt0 = rk00; kt1 = rk01; }
  tf2x32(kt0, kt1, 0u, (uint32_t)phase, c0, c1);
}

__device__ __forceinline__ void slice6(float w, signed char sb[6]) {
  long long v = __double2ll_rn((double)w * 0x1p48);
#pragma unroll
  for (int s = 0; s < 6; s++) {
    signed char b = (signed char)(v & 0xFF);
    sb[s] = b;
    v = (v - b) >> 8;
  }
}

// ---------------------------------------------------------------------------
// Prep: W [1024][4096] f32 -> Ws[6][1024][4096] i8 and WsT[6][4096][1024] i8
__global__ __launch_bounds__(256)
void prepW(const float* __restrict__ W, signed char* __restrict__ Ws,
           signed char* __restrict__ WsT) {
  __shared__ float tl[64][65];
  int bi = blockIdx.x >> 6;   // n-tile 0..15
  int bj = blockIdx.x & 63;   // k-tile 0..63
  int n0 = bi * 64, k0 = bj * 64;
  int tid = threadIdx.x;
#pragma unroll
  for (int it = 0; it < 4; it++) {
    int r = (tid >> 4) + it * 16, c4 = (tid & 15) * 4;
    float4 q = *(const float4*)(W + (size_t)(n0 + r) * NVV + k0 + c4);
    tl[r][c4] = q.x; tl[r][c4 + 1] = q.y; tl[r][c4 + 2] = q.z; tl[r][c4 + 3] = q.w;
  }
  __syncthreads();
#pragma unroll
  for (int it = 0; it < 4; it++) {
    int r = (tid >> 4) + it * 16, c4 = (tid & 15) * 4;
    unsigned int pk[6] = {0, 0, 0, 0, 0, 0};
    for (int j = 0; j < 4; j++) {
      signed char sb[6]; slice6(tl[r][c4 + j], sb);
      for (int s = 0; s < 6; s++) pk[s] |= ((unsigned)(unsigned char)sb[s]) << (8 * j);
    }
    for (int s = 0; s < 6; s++)
      *(unsigned int*)(Ws + (size_t)s * NHH * NVV + (size_t)(n0 + r) * NVV + k0 + c4) = pk[s];
  }
#pragma unroll
  for (int it = 0; it < 4; it++) {
    int r = (tid >> 4) + it * 16, c4 = (tid & 15) * 4;
    unsigned int pk[6] = {0, 0, 0, 0, 0, 0};
    for (int j = 0; j < 4; j++) {
      signed char sb[6]; slice6(tl[c4 + j][r], sb);
      for (int s = 0; s < 6; s++) pk[s] |= ((unsigned)(unsigned char)sb[s]) << (8 * j);
    }
    for (int s = 0; s < 6; s++)
      *(unsigned int*)(WsT + (size_t)s * NVV * NHH + (size_t)(k0 + r) * NHH + n0 + c4) = pk[s];
  }
}

// Prep: v [4096][2048] f32 bits -> vT [2048][4096] i8
__global__ __launch_bounds__(256)
void prepVT(const float* __restrict__ v, signed char* __restrict__ vT) {
  __shared__ float tl[64][65];
  int bi = blockIdx.x >> 5;  // i-tile 0..63
  int bj = blockIdx.x & 31;  // c-tile 0..31
  int i0 = bi * 64, c0 = bj * 64;
  int tid = threadIdx.x;
#pragma unroll
  for (int it = 0; it < 4; it++) {
    int r = (tid >> 4) + it * 16, c4 = (tid & 15) * 4;
    float4 q = *(const float4*)(v + (size_t)(i0 + r) * CC + c0 + c4);
    tl[r][c4] = q.x; tl[r][c4 + 1] = q.y; tl[r][c4 + 2] = q.z; tl[r][c4 + 3] = q.w;
  }
  __syncthreads();
#pragma unroll
  for (int it = 0; it < 4; it++) {
    int cc = (tid >> 4) + it * 16, i4 = (tid & 15) * 4;
    unsigned int pk = 0;
    for (int j = 0; j < 4; j++)
      pk |= ((unsigned)(tl[i4 + j][cc] != 0.0f ? 1 : 0)) << (8 * j);
    *(unsigned int*)(vT + (size_t)(c0 + cc) * NVV + i0 + i4) = pk;
  }
}

// ---------------------------------------------------------------------------
// Stage 0: WvT[c][n] f64 = (vT @ Ws^T)*2^-48. M=2048(c), N=1024(n), K=4096.
// Block 128c x 64n (4 waves, each 64c x 32n via 2 m-tiles). Grid 256, swizzled.
__global__ __launch_bounds__(256)
void s0k(const signed char* __restrict__ vT, const signed char* __restrict__ Ws,
         double* __restrict__ WvT) {
  int wave = threadIdx.x >> 6, lane = threadIdx.x & 63;
  int lrow = lane & 31, lhalf = lane >> 5;
  int xcd = blockIdx.x & 7, idx = blockIdx.x >> 3;     // idx 0..31
  int bn = xcd * 2 + (idx >> 4);                        // 0..15
  int bm = idx & 15;                                    // 0..15
  int m0 = bm * 128 + (wave & 1) * 64;
  int n0 = bn * 64 + (wave >> 1) * 32;

  v16i acc[2][6];
  for (int mt = 0; mt < 2; mt++)
    for (int s = 0; s < 6; s++)
      for (int e = 0; e < 16; e++) acc[mt][s][e] = 0;

  const signed char* a0 = vT + (size_t)(m0 + lrow) * NVV + 16 * lhalf;
  const signed char* a1 = a0 + (size_t)32 * NVV;
  const signed char* bB = Ws + (size_t)(n0 + lrow) * NVV + 16 * lhalf;
#pragma unroll 2
  for (int kb = 0; kb < NVV; kb += 32) {
    v4i af0 = *(const v4i*)(a0 + kb);
    v4i af1 = *(const v4i*)(a1 + kb);
#pragma unroll
    for (int s = 0; s < 6; s++) {
      v4i bf = *(const v4i*)(bB + (size_t)s * NHH * NVV + kb);
      acc[0][s] = __builtin_amdgcn_mfma_i32_32x32x32_i8(af0, bf, acc[0][s], 0, 0, 0);
      acc[1][s] = __builtin_amdgcn_mfma_i32_32x32x32_i8(af1, bf, acc[1][s], 0, 0, 0);
    }
  }
#pragma unroll
  for (int mt = 0; mt < 2; mt++)
#pragma unroll
    for (int e = 0; e < 16; e++) {
      int row = (e & 3) + 8 * (e >> 2) + 4 * lhalf;
      double lg = 0;
#pragma unroll
      for (int s = 0; s < 6; s++) lg += (double)acc[mt][s][e] * SC6[s];
      WvT[(size_t)(m0 + mt * 32 + row) * NHH + n0 + lrow] = lg;
    }
}

// Serial step t: logit = WvT + hid_bias; sample h, r. Also STORES hid_bias
// (fp64) to hb64[c][n] for stage-3 reuse.
__global__ __launch_bounds__(256)
void step1(const float* __restrict__ U, const float* __restrict__ rin,
           float* __restrict__ rout, const double* __restrict__ WvT,
           const float* __restrict__ b_h, const float* __restrict__ b_init,
           float* __restrict__ rt, unsigned char* __restrict__ hT,
           double* __restrict__ hb64, int t, uint32_t key0, uint32_t key1) {
  __shared__ double red[2][4][32];
  int tid = threadIdx.x;
  int b = tid & 31, ks = (tid >> 5) & 3, rr = tid >> 7;
  int n = blockIdx.x * 2 + rr;
  double a0 = 0, a1 = 0, a2 = 0, a3 = 0;
  if (t > 0) {
    const float* urow = U + (size_t)n * NHH + ks * 256;
    const float* rp = rin + b;
    for (int k = 0; k < 256; k += 4) {
      float4 uq = *(const float4*)(urow + k);
      int kk = (ks * 256 + k) * 32;
      a0 += (double)uq.x * (double)rp[kk];
      a1 += (double)uq.y * (double)rp[kk + 32];
      a2 += (double)uq.z * (double)rp[kk + 64];
      a3 += (double)uq.w * (double)rp[kk + 96];
    }
  }
  red[rr][ks][b] = (a0 + a1) + (a2 + a3);
  __syncthreads();
  if (ks == 0) {
    double s = red[rr][0][b] + red[rr][1][b] + red[rr][2][b] + red[rr][3][b];
    double hbv = (t > 0) ? (s + (double)b_h[n]) : (double)b_init[n];
    double wv = WvT[(size_t)(t * 32 + b) * NHH + n];
    float p32, bit;
    bern_sample(wv + hbv, key0, key1, (uint32_t)(n * 32 + b), p32, bit);
    rt[(size_t)n * CC + t * 32 + b] = p32;
    rout[n * 32 + b] = p32;
    hT[(size_t)(t * 32 + b) * NHH + n] = (unsigned char)(bit != 0.0f ? 1 : 0);
    hb64[(size_t)(t * 32 + b) * NHH + n] = hbv;
  }
}

// Stages 2/4: out[i][c] = bern(sigma(W^T@x + b_v)). A=WsT(6 slices), B=bits.
// Block 64i x 128c (4 waves, each 32i x 64c via 2 c-tiles). Grid 1024, swizzled.
__global__ __launch_bounds__(256, 2)
void sV(const signed char* __restrict__ WsT, const signed char* __restrict__ xT,
        const float* __restrict__ b_v, unsigned char* __restrict__ bitT,
        float* __restrict__ f32out, int phase,
        uint32_t rk00, uint32_t rk01, uint32_t rk10, uint32_t rk11) {
  int wave = threadIdx.x >> 6, lane = threadIdx.x & 63;
  int lrow = lane & 31, lhalf = lane >> 5;
  int xcd = blockIdx.x & 7, idx = blockIdx.x >> 3;     // idx 0..127
  int bi = xcd * 8 + (idx & 7);                         // 0..63
  int bc = idx >> 3;                                    // 0..15
  int m0 = bi * 64 + (wave & 1) * 32;                   // i
  int n0 = bc * 128 + (wave >> 1) * 64;                 // c

  v16i acc[2][6];
  for (int ct = 0; ct < 2; ct++)
    for (int s = 0; s < 6; s++)
      for (int e = 0; e < 16; e++) acc[ct][s][e] = 0;

  const signed char* b0 = xT + (size_t)(n0 + lrow) * NHH + 16 * lhalf;
  const signed char* b1 = b0 + (size_t)32 * NHH;
  const signed char* aB = WsT + (size_t)(m0 + lrow) * NHH + 16 * lhalf;
#pragma unroll 2
  for (int kb = 0; kb < NHH; kb += 32) {
    v4i bf0 = *(const v4i*)(b0 + kb);
    v4i bf1 = *(const v4i*)(b1 + kb);
#pragma unroll
    for (int s = 0; s < 6; s++) {
      v4i af = *(const v4i*)(aB + (size_t)s * NVV * NHH + kb);
      acc[0][s] = __builtin_amdgcn_mfma_i32_32x32x32_i8(af, bf0, acc[0][s], 0, 0, 0);
      acc[1][s] = __builtin_amdgcn_mfma_i32_32x32x32_i8(af, bf1, acc[1][s], 0, 0, 0);
    }
  }

#pragma unroll
  for (int ct = 0; ct < 2; ct++) {
    int tt = (n0 + ct * 32) >> 5;
    uint32_t ck0, ck1;
    step_key(tt, phase, rk00, rk01, rk10, rk11, ck0, ck1);
    int c = n0 + ct * 32 + lrow;
    if (bitT) {
#pragma unroll
      for (int g = 0; g < 4; g++) {
        unsigned int packed = 0;
#pragma unroll
        for (int q = 0; q < 4; q++) {
          int e = g * 4 + q;
          int i = m0 + q + 8 * g + 4 * lhalf;
          double lg = (double)b_v[i];
#pragma unroll
          for (int s = 0; s < 6; s++) lg += (double)acc[ct][s][e] * SC6[s];
          float p32, bit;
          bern_sample(lg, ck0, ck1, (uint32_t)(i * 32 + lrow), p32, bit);
          (void)p32;
          packed |= ((unsigned)(bit != 0.0f ? 1 : 0)) << (8 * q);
        }
        *(unsigned int*)(bitT + (size_t)c * NVV + m0 + 8 * g + 4 * lhalf) = packed;
      }
    } else {
#pragma unroll
      for (int e = 0; e < 16; e++) {
        int i = m0 + (e & 3) + 8 * (e >> 2) + 4 * lhalf;
        double lg = (double)b_v[i];
#pragma unroll
        for (int s = 0; s < 6; s++) lg += (double)acc[ct][s][e] * SC6[s];
        float p32, bit;
        bern_sample(lg, ck0, ck1, (uint32_t)(i * 32 + lrow), p32, bit);
        (void)p32;
        f32out[(size_t)i * CC + c] = bit;
      }
    }
  }
}

// Stage 3: logit = W@vm + hb64; sample h2 -> h2T + rmodel.
// Same tiling as s0k. M=2048(c), N=1024(n), K=4096.
__global__ __launch_bounds__(256)
void s3k(const signed char* __restrict__ vmT, const signed char* __restrict__ Ws,
         const double* __restrict__ hb64,
         unsigned char* __restrict__ h2T, float* __restrict__ rmodel,
         uint32_t rk00, uint32_t rk01, uint32_t rk10, uint32_t rk11) {
  int wave = threadIdx.x >> 6, lane = threadIdx.x & 63;
  int lrow = lane & 31, lhalf = lane >> 5;
  int xcd = blockIdx.x & 7, idx = blockIdx.x >> 3;
  int bn = xcd * 2 + (idx >> 4);
  int bm = idx & 15;
  int m0 = bm * 128 + (wave & 1) * 64;   // c
  int n0 = bn * 64 + (wave >> 1) * 32;   // n

  v16i acc[2][6];
  for (int mt = 0; mt < 2; mt++)
    for (int s = 0; s < 6; s++)
      for (int e = 0; e < 16; e++) acc[mt][s][e] = 0;

  const signed char* a0 = vmT + (size_t)(m0 + lrow) * NVV + 16 * lhalf;
  const signed char* a1 = a0 + (size_t)32 * NVV;
  const signed char* bB = Ws + (size_t)(n0 + lrow) * NVV + 16 * lhalf;
#pragma unroll 2
  for (int kb = 0; kb < NVV; kb += 32) {
    v4i af0 = *(const v4i*)(a0 + kb);
    v4i af1 = *(const v4i*)(a1 + kb);
#pragma unroll
    for (int s = 0; s < 6; s++) {
      v4i bf = *(const v4i*)(bB + (size_t)s * NHH * NVV + kb);
      acc[0][s] = __builtin_amdgcn_mfma_i32_32x32x32_i8(af0, bf, acc[0][s], 0, 0, 0);
      acc[1][s] = __builtin_amdgcn_mfma_i32_32x32x32_i8(af1, bf, acc[1][s], 0, 0, 0);
    }
  }

  int n = n0 + lrow;
#pragma unroll
  for (int mt = 0; mt < 2; mt++) {
    int tt = (m0 + mt * 32) >> 5;
    uint32_t ck0, ck1;
    step_key(tt, 2, rk00, rk01, rk10, rk11, ck0, ck1);
#pragma unroll
    for (int e = 0; e < 16; e++) {
      int row = (e & 3) + 8 * (e >> 2) + 4 * lhalf;
      int c = m0 + mt * 32 + row;
      double lg = 0;
#pragma unroll
      for (int s = 0; s < 6; s++) lg += (double)acc[mt][s][e] * SC6[s];
      lg += hb64[(size_t)c * NHH + n];
      float p32, bit;
      bern_sample(lg, ck0, ck1, (uint32_t)(n * 32 + row), p32, bit);
      (void)p32;
      h2T[(size_t)c * NHH + n] = (unsigned char)(bit != 0.0f ? 1 : 0);
      rmodel[(size_t)n * CC + c] = bit;
    }
  }
}

// ---------------------------------------------------------------------------
static void tf_split(const uint32_t key[2], int n, uint32_t out[][2]) {
  for (int i = 0; i < n; i++)
    tf2x32(key[0], key[1], 0u, (uint32_t)i, out[i][0], out[i][1]);
}

extern "C" void kernel_launch(void* const* d_in, const int* in_sizes, int n_in,
                              void* d_out, int out_size, void* d_ws, size_t ws_size,
                              hipStream_t stream) {
  const float* v      = (const float*)d_in[0];
  const float* W      = (const float*)d_in[1];
  const float* U      = (const float*)d_in[2];
  const float* b_v    = (const float*)d_in[3];
  const float* b_h    = (const float*)d_in[4];
  const float* b_init = (const float*)d_in[5];

  float* out    = (float*)d_out;
  float* vmodel = out;                           // [4096][2048]
  float* rmodel = out + (size_t)NVV * CC;        // [1024][2048]
  float* rt     = rmodel + (size_t)NHH * CC;     // [1024][2048]

  char* wsb = (char*)d_ws;
  signed char* Ws   = (signed char*)wsb;                         // 24 MB
  signed char* WsT  = (signed char*)(wsb + 25165824);            // 24 MB
  signed char* vT   = (signed char*)(wsb + 50331648);            // 8 MB
  signed char* vmT  = (signed char*)(wsb + 58720256);            // 8 MB
  unsigned char* hT = (unsigned char*)(wsb + 67108864);          // 2 MB
  unsigned char* h2T= (unsigned char*)(wsb + 69206016);          // 2 MB
  double* WvT       = (double*)(wsb + 71303168);                 // 16 MB
  double* hb64      = (double*)(wsb + 88080384);                 // 16 MB
  float* r_cmp      = (float*)(wsb + 104857600);                 // 2 x 128 KB

  uint32_t root[2] = {0u, 42u};
  uint32_t rk[2][2];  tf_split(root, 2, rk);
  uint32_t tk[63][2]; tf_split(rk[1], 63, tk);

  // --- prep ---
  hipLaunchKernelGGL(prepW, dim3(1024), dim3(256), 0, stream, W, Ws, WsT);
  hipLaunchKernelGGL(prepVT, dim3(2048), dim3(256), 0, stream, v, vT);

  // --- stage 0: WvT = W@v (all t) ---
  hipLaunchKernelGGL(s0k, dim3(256), dim3(256), 0, stream, vT, Ws, WvT);

  // --- stage 1: serial recurrence (writes rt, hT, hb64) ---
  for (int t = 0; t < TT; t++) {
    uint32_t key_t0 = t ? tk[t - 1][0] : rk[0][0];
    uint32_t key_t1 = t ? tk[t - 1][1] : rk[0][1];
    uint32_t ck0, ck1;
    tf2x32(key_t0, key_t1, 0u, 0u, ck0, ck1);
    float* rin  = r_cmp + ((t + 1) & 1) * 32768;
    float* rout = r_cmp + (t & 1) * 32768;
    hipLaunchKernelGGL(step1, dim3(512), dim3(256), 0, stream,
                       U, rin, rout, WvT, b_h, b_init, rt, hT, hb64, t, ck0, ck1);
  }

  // --- stage 2: vm bits -> vmT ---
  hipLaunchKernelGGL(sV, dim3(1024), dim3(256), 0, stream,
                     WsT, (const signed char*)hT, b_v, (unsigned char*)vmT,
                     (float*)nullptr, 1, rk[0][0], rk[0][1], rk[1][0], rk[1][1]);

  // --- stage 3: h2 bits + rmodel ---
  hipLaunchKernelGGL(s3k, dim3(256), dim3(256), 0, stream,
                     vmT, Ws, hb64, h2T, rmodel,
                     rk[0][0], rk[0][1], rk[1][0], rk[1][1]);

  // --- stage 4: vmodel ---
  hipLaunchKernelGGL(sV, dim3(1024), dim3(256), 0, stream,
                     WsT, (const signed char*)h2T, b_v, (unsigned char*)nullptr,
                     vmodel, 3, rk[0][0], rk[0][1], rk[1][0], rk[1][1]);

  (void)in_sizes; (void)n_in; (void)out_size; (void)ws_size;
}